// Round 2
// baseline (843.281 us; speedup 1.0000x reference)
//
#include <hip/hip_runtime.h>

typedef _Float16 f16x8 __attribute__((ext_vector_type(8)));
typedef float f32x4 __attribute__((ext_vector_type(4)));
typedef unsigned short us4v __attribute__((ext_vector_type(4)));

__device__ inline unsigned short f16b(float v) {
    _Float16 h = (_Float16)v;
    return __builtin_bit_cast(unsigned short, h);
}

__device__ inline void atomAddF(float* p, float v) {
    __hip_atomic_fetch_add(p, v, __ATOMIC_RELAXED, __HIP_MEMORY_SCOPE_AGENT);
}

// ---------------- one-time conversion fp32 -> fp16 ----------------
__global__ __launch_bounds__(256) void cvt_f16(const float* __restrict__ in,
                                               unsigned short* __restrict__ out, int n) {
    int i = blockIdx.x * 256 + threadIdx.x;
    if (i * 4 < n) {
        float4 v = ((const float4*)in)[i];
        us4v o;
        o[0] = f16b(v.x); o[1] = f16b(v.y); o[2] = f16b(v.z); o[3] = f16b(v.w);
        ((us4v*)out)[i] = o;
    }
}

// P [2048][4096][2] f32  ->  PT [4096][4096] f16 where PT[m][n*2+p] = P[n][m][p]
__global__ __launch_bounds__(256) void transpose_p(const float* __restrict__ P,
                                                   unsigned short* __restrict__ PT) {
    __shared__ unsigned int lds[64][33];
    int bid = blockIdx.x;
    int m0 = (bid & 127) * 32;   // 128 tiles over M=4096
    int n0 = (bid >> 7) * 64;    // 32 tiles over N=2048
    int tid = threadIdx.x;
    const float2* P2 = (const float2*)P;  // index n*4096+m
    #pragma unroll
    for (int it = 0; it < 8; ++it) {
        int idx = it * 256 + tid;
        int nl = idx >> 5, ml = idx & 31;
        float2 v = P2[(size_t)(n0 + nl) * 4096 + (m0 + ml)];
        unsigned int pk = (unsigned int)f16b(v.x) | ((unsigned int)f16b(v.y) << 16);
        lds[nl][ml] = pk;
    }
    __syncthreads();
    unsigned int* PTu = (unsigned int*)PT;  // index m*2048 + n
    #pragma unroll
    for (int it = 0; it < 8; ++it) {
        int idx = it * 256 + tid;
        int ml = idx >> 6, nl = idx & 63;
        PTu[(size_t)(m0 + ml) * 2048 + (n0 + nl)] = lds[nl][ml];
    }
}

// ---------------- per-layer B-matrix build (fragment layout) ----------------
// B1 (K=14336): rows m*3+j from (hx, w1a=[J*Fin,Fout]); rows 6144+m*2+p from (hy, w1b=[2*Fin,Fout])
// B2 (K=16384): rows m*3+j from (hy, w2a); rows 12288+n*2+p from (hx, w2b)
// Fragment layout: elem index ((t*2+h)*64+lane)*8+e holds B[k=t*32+(lane>>4)*8+e][g=h*16+(lane&15)]
__global__ __launch_bounds__(256) void build_b(
    const float* __restrict__ hx, const float* __restrict__ hy, int Fin, int Fout, int buildB2,
    const float* __restrict__ w1a, const float* __restrict__ w1b,
    const float* __restrict__ w2a, const float* __restrict__ w2b,
    unsigned short* __restrict__ B1f, unsigned short* __restrict__ B2f,
    float* __restrict__ zeroreg, int nzero) {
    int tid = blockIdx.x * 256 + threadIdx.x;
    if (tid < nzero) zeroreg[tid] = 0.f;
    const int NB1 = 14336 * 32;
    if (tid < NB1) {
        int e = tid & 7, lane = (tid >> 3) & 63, h = (tid >> 9) & 1, t = tid >> 10;
        int k = (t << 5) | ((lane >> 4) << 3) | e;
        int g = (h << 4) | (lane & 15);
        float v = 0.f;
        if (g < Fout) {
            float a = 0.f;
            if (k < 6144) {
                int m = k / 3, j = k - 3 * m;
                const float* hr = hx + m * Fin;
                const float* wc = w1a + j * Fin * Fout + g;
                for (int f = 0; f < Fin; ++f) a += hr[f] * wc[f * Fout];
            } else {
                int k2 = k - 6144; int m = k2 >> 1, p = k2 & 1;
                const float* hr = hy + m * Fin;
                const float* wc = w1b + p * Fin * Fout + g;
                for (int f = 0; f < Fin; ++f) a += hr[f] * wc[f * Fout];
            }
            v = a;
        }
        B1f[tid] = f16b(v);
    } else if (buildB2) {
        int t2 = tid - NB1;
        if (t2 < 16384 * 32) {
            int e = t2 & 7, lane = (t2 >> 3) & 63, h = (t2 >> 9) & 1, t = t2 >> 10;
            int k = (t << 5) | ((lane >> 4) << 3) | e;
            int g = (h << 4) | (lane & 15);
            float v = 0.f;
            if (g < Fout) {
                float a = 0.f;
                if (k < 12288) {
                    int m = k / 3, j = k - 3 * m;
                    const float* hr = hy + m * Fin;
                    const float* wc = w2a + j * Fin * Fout + g;
                    for (int f = 0; f < Fin; ++f) a += hr[f] * wc[f * Fout];
                } else {
                    int k2 = k - 12288; int n = k2 >> 1, p = k2 & 1;
                    const float* hr = hx + n * Fin;
                    const float* wc = w2b + p * Fin * Fout + g;
                    for (int f = 0; f < Fin; ++f) a += hr[f] * wc[f * Fout];
                }
                v = a;
            }
            B2f[t2] = f16b(v);
        }
    }
}

// ---------------- split-K MFMA GEMM (both branches in one grid) ----------------
// x-branch: 16 mwgs (128 rows each) x 14 ksegs ; y-branch: 32 mwgs x 16 ksegs
__global__ __launch_bounds__(256) void gemm_kernel(
    const unsigned short* __restrict__ Wb, const unsigned short* __restrict__ Pb,
    const unsigned short* __restrict__ WLb, const unsigned short* __restrict__ PTb,
    const unsigned short* __restrict__ B1f, const unsigned short* __restrict__ B2f,
    float* __restrict__ zx, float* __restrict__ zy, int nwgx) {
    int bid = blockIdx.x;
    const unsigned short *A1, *A2, *Bf;
    float* Z;
    int K1, K2len, split, seg, Mbase;
    if (bid < nwgx) {
        A1 = Wb; A2 = Pb; Bf = B1f; Z = zx;
        K1 = 6144; K2len = 8192; split = 6;
        int mwg = bid / 14; seg = bid % 14;
        Mbase = mwg * 128;
    } else {
        int b2 = bid - nwgx;
        A1 = WLb; A2 = PTb; Bf = B2f; Z = zy;
        K1 = 12288; K2len = 4096; split = 12;
        int mwg = b2 / 16; seg = b2 % 16;
        Mbase = mwg * 128;
    }
    int wid = threadIdx.x >> 6, lane = threadIdx.x & 63;
    int rowbase = Mbase + wid * 32;
    int kb = seg << 10;
    const unsigned short* Ab; int rowlen, kloc;
    if (seg < split) { Ab = A1; rowlen = K1; kloc = kb; }
    else             { Ab = A2; rowlen = K2len; kloc = kb - K1; }
    const unsigned short* ap0 = Ab + (size_t)(rowbase + (lane & 15)) * rowlen + kloc + ((lane >> 4) << 3);
    const unsigned short* ap1 = ap0 + (size_t)16 * rowlen;
    const unsigned short* bp = Bf + ((size_t)(kb >> 5)) * 1024 + lane * 8;
    f32x4 acc00 = {0.f,0.f,0.f,0.f}, acc01 = {0.f,0.f,0.f,0.f};
    f32x4 acc10 = {0.f,0.f,0.f,0.f}, acc11 = {0.f,0.f,0.f,0.f};
    #pragma unroll 4
    for (int ks = 0; ks < 32; ++ks) {
        f16x8 a0 = *(const f16x8*)ap0;
        f16x8 a1 = *(const f16x8*)ap1;
        f16x8 b0 = *(const f16x8*)bp;
        f16x8 b1 = *(const f16x8*)(bp + 512);
        acc00 = __builtin_amdgcn_mfma_f32_16x16x32_f16(a0, b0, acc00, 0, 0, 0);
        acc10 = __builtin_amdgcn_mfma_f32_16x16x32_f16(a1, b0, acc10, 0, 0, 0);
        acc01 = __builtin_amdgcn_mfma_f32_16x16x32_f16(a0, b1, acc01, 0, 0, 0);
        acc11 = __builtin_amdgcn_mfma_f32_16x16x32_f16(a1, b1, acc11, 0, 0, 0);
        ap0 += 32; ap1 += 32; bp += 1024;
    }
    int col = lane & 15, r0 = (lane >> 4) << 2;
    float* z0 = Z + (size_t)(rowbase + r0) * 32 + col;
    #pragma unroll
    for (int r = 0; r < 4; ++r) {
        atomAddF(z0 + (size_t)r * 32,             acc00[r]);
        atomAddF(z0 + (size_t)r * 32 + 16,        acc01[r]);
        atomAddF(z0 + (size_t)(r + 16) * 32,      acc10[r]);
        atomAddF(z0 + (size_t)(r + 16) * 32 + 16, acc11[r]);
    }
}

// ---------------- post-GEMM: column stats of post-ReLU z ----------------
// blocks 0..255: x (8 rows each of 2048); 256..767: y (8 rows each of 4096)
__global__ __launch_bounds__(256) void stats_kernel(
    const float* __restrict__ zx, const float* __restrict__ zy,
    const float* __restrict__ bx, const float* __restrict__ by,
    float* __restrict__ stats) {
    __shared__ float ls[4][32];
    __shared__ float ls2[4][32];
    int bid = blockIdx.x, tid = threadIdx.x;
    const float* Z; const float* b; float* st; int rowbase;
    if (bid < 256) { Z = zx; b = bx; st = stats;      rowbase = bid * 8; }
    else           { Z = zy; b = by; st = stats + 64; rowbase = (bid - 256) * 8; }
    int col = tid & 31, r = tid >> 5;
    float z = Z[(size_t)(rowbase + r) * 32 + col] + b[col];
    if (col < 16) z = fmaxf(z, 0.f);
    float s = z, s2 = z * z;
    s  += __shfl_xor(s, 32);
    s2 += __shfl_xor(s2, 32);
    int w = tid >> 6;
    if ((tid & 63) < 32) { ls[w][col] = s; ls2[w][col] = s2; }
    __syncthreads();
    if (tid < 32) {
        float a = ls[0][tid] + ls[1][tid] + ls[2][tid] + ls[3][tid];
        float q = ls2[0][tid] + ls2[1][tid] + ls2[2][tid] + ls2[3][tid];
        atomAddF(&st[tid], a);
        atomAddF(&st[32 + tid], q);
    }
}

// ---------------- batchnorm normalize -> next hx/hy ----------------
__global__ __launch_bounds__(256) void bn_kernel(
    const float* __restrict__ zx, const float* __restrict__ zy,
    const float* __restrict__ bx, const float* __restrict__ by,
    const float* __restrict__ gx, const float* __restrict__ btx,
    const float* __restrict__ gy, const float* __restrict__ bty,
    const float* __restrict__ stats,
    float* __restrict__ hxn, float* __restrict__ hyn) {
    int tid = blockIdx.x * 256 + threadIdx.x;
    const float *Z, *b, *g, *bt, *st; float* out; int idx; float invn;
    if (tid < 65536) { Z = zx; b = bx; g = gx; bt = btx; st = stats;      out = hxn; idx = tid;          invn = 1.f / 2048.f; }
    else             { Z = zy; b = by; g = gy; bt = bty; st = stats + 64; out = hyn; idx = tid - 65536;  invn = 1.f / 4096.f; }
    int col = idx & 31;
    float z = Z[idx] + b[col];
    if (col < 16) z = fmaxf(z, 0.f);
    float mean = st[col] * invn;
    float var = st[32 + col] * invn - mean * mean;
    float inv = rsqrtf(var + 1e-5f);
    out[idx] = g[col] * (z - mean) * inv + bt[col];
}

// ---------------- final output: out[n][c] = zfin[n][c] + bl[c] ----------------
__global__ __launch_bounds__(256) void out_kernel(const float* __restrict__ zx,
                                                  const float* __restrict__ bl,
                                                  float* __restrict__ out) {
    int tid = blockIdx.x * 256 + threadIdx.x;
    if (tid < 4096) {
        int n = tid >> 1, c = tid & 1;
        out[tid] = zx[n * 32 + c] + bl[c];
    }
}

extern "C" void kernel_launch(void* const* d_in, const int* in_sizes, int n_in,
                              void* d_out, int out_size, void* d_ws, size_t ws_size,
                              hipStream_t stream) {
    const float* W    = (const float*)d_in[0];
    const float* x    = (const float*)d_in[1];
    const float* WL   = (const float*)d_in[2];
    const float* y    = (const float*)d_in[3];
    const float* P    = (const float*)d_in[4];
    const float* wx2x0 = (const float*)d_in[5];
    const float* wy2x0 = (const float*)d_in[6];
    const float* bx0   = (const float*)d_in[7];
    const float* wy2y0 = (const float*)d_in[8];
    const float* wx2y0 = (const float*)d_in[9];
    const float* by0   = (const float*)d_in[10];
    const float* gx0   = (const float*)d_in[11];
    const float* btx0  = (const float*)d_in[12];
    const float* gy0   = (const float*)d_in[13];
    const float* bty0  = (const float*)d_in[14];
    const float* wx2x_m = (const float*)d_in[15];
    const float* wy2x_m = (const float*)d_in[16];
    const float* bx_m   = (const float*)d_in[17];
    const float* wy2y_m = (const float*)d_in[18];
    const float* wx2y_m = (const float*)d_in[19];
    const float* by_m   = (const float*)d_in[20];
    const float* gx_m   = (const float*)d_in[21];
    const float* btx_m  = (const float*)d_in[22];
    const float* gy_m   = (const float*)d_in[23];
    const float* bty_m  = (const float*)d_in[24];
    const float* wlx = (const float*)d_in[25];
    const float* wly = (const float*)d_in[26];
    const float* bl  = (const float*)d_in[27];

    char* base = (char*)d_ws;
    unsigned short* Wb  = (unsigned short*)(base + 0);
    unsigned short* Pb  = (unsigned short*)(base + 25165824);
    unsigned short* WLb = (unsigned short*)(base + 58720256);
    unsigned short* PTb = (unsigned short*)(base + 159383552);
    unsigned short* B1f = (unsigned short*)(base + 192937984);
    unsigned short* B2f = (unsigned short*)(base + 193855488);
    float* zx    = (float*)(base + 194904064);
    float* zy    = (float*)(base + 195166208);
    float* stats = (float*)(base + 195690496);
    float* hx0   = (float*)(base + 195691008);
    float* hx1   = (float*)(base + 195953152);
    float* hy0   = (float*)(base + 196215296);
    float* hy1   = (float*)(base + 196739584);

    // one-time conversions
    cvt_f16<<<12288, 256, 0, stream>>>(W, Wb, 12582912);
    cvt_f16<<<16384, 256, 0, stream>>>(P, Pb, 16777216);
    cvt_f16<<<49152, 256, 0, stream>>>(WL, WLb, 50331648);
    transpose_p<<<4096, 256, 0, stream>>>(P, PTb);

    const int ZCNT = 196736;  // zx (65536) + zy (131072) + stats (128) floats, contiguous

    // layer 0 (Fin = 1)
    build_b<<<3840, 256, 0, stream>>>(x, y, 1, 32, 1, wx2x0, wy2x0, wy2y0, wx2y0, B1f, B2f, zx, ZCNT);
    gemm_kernel<<<736, 256, 0, stream>>>(Wb, Pb, WLb, PTb, B1f, B2f, zx, zy, 224);
    stats_kernel<<<768, 256, 0, stream>>>(zx, zy, bx0, by0, stats);
    bn_kernel<<<768, 256, 0, stream>>>(zx, zy, bx0, by0, gx0, btx0, gy0, bty0, stats, hx0, hy0);

    float* hx = hx0; float* hy = hy0; float* hxn = hx1; float* hyn = hy1;
    for (int i = 0; i < 6; ++i) {
        const float* wxx = wx2x_m + i * 96 * 32;
        const float* wyx = wy2x_m + i * 64 * 32;
        const float* wyy = wy2y_m + i * 96 * 32;
        const float* wxy = wx2y_m + i * 64 * 32;
        const float* bxi = bx_m + i * 32;
        const float* byi = by_m + i * 32;
        const float* gxi = gx_m + i * 32;
        const float* btxi = btx_m + i * 32;
        const float* gyi = gy_m + i * 32;
        const float* btyi = bty_m + i * 32;
        build_b<<<3840, 256, 0, stream>>>(hx, hy, 32, 32, 1, wxx, wyx, wyy, wxy, B1f, B2f, zx, ZCNT);
        gemm_kernel<<<736, 256, 0, stream>>>(Wb, Pb, WLb, PTb, B1f, B2f, zx, zy, 224);
        stats_kernel<<<768, 256, 0, stream>>>(zx, zy, bxi, byi, stats);
        bn_kernel<<<768, 256, 0, stream>>>(zx, zy, bxi, byi, gxi, btxi, gyi, btyi, stats, hxn, hyn);
        float* t;
        t = hx; hx = hxn; hxn = t;
        t = hy; hy = hyn; hyn = t;
    }

    // final layer: x-branch only, Fout = 2
    build_b<<<1792, 256, 0, stream>>>(hx, hy, 32, 2, 0, wlx, wly, nullptr, nullptr, B1f, B2f, zx, 65536);
    gemm_kernel<<<224, 256, 0, stream>>>(Wb, Pb, WLb, PTb, B1f, B2f, zx, zy, 224);
    out_kernel<<<16, 256, 0, stream>>>(zx, bl, (float*)d_out);
}

// Round 3
// 710.208 us; speedup vs baseline: 1.1874x; 1.1874x over previous
//
#include <hip/hip_runtime.h>

typedef _Float16 f16x8 __attribute__((ext_vector_type(8)));
typedef float f32x4 __attribute__((ext_vector_type(4)));
typedef unsigned short us4v __attribute__((ext_vector_type(4)));

__device__ inline unsigned short f16b(float v) {
    _Float16 h = (_Float16)v;
    return __builtin_bit_cast(unsigned short, h);
}

__device__ inline void atomAddF(float* p, float v) {
    __hip_atomic_fetch_add(p, v, __ATOMIC_RELAXED, __HIP_MEMORY_SCOPE_AGENT);
}

// ---------------- one-time conversion fp32 -> fp16 (W, P, WL fused) ----------------
// float4 units: W 3145728, P 4194304, WL 12582912; total 19922944 -> 77824 WGs
__global__ __launch_bounds__(256) void cvt_all(const float* __restrict__ W, const float* __restrict__ P,
                                               const float* __restrict__ WL,
                                               unsigned short* __restrict__ Wb, unsigned short* __restrict__ Pb,
                                               unsigned short* __restrict__ WLb) {
    int i = blockIdx.x * 256 + threadIdx.x;
    const float* src; unsigned short* dst; int idx;
    if (i < 3145728)               { src = W;  dst = Wb;  idx = i; }
    else if (i < 3145728 + 4194304){ src = P;  dst = Pb;  idx = i - 3145728; }
    else                           { src = WL; dst = WLb; idx = i - (3145728 + 4194304); }
    float4 v = ((const float4*)src)[idx];
    us4v o;
    o[0] = f16b(v.x); o[1] = f16b(v.y); o[2] = f16b(v.z); o[3] = f16b(v.w);
    ((us4v*)dst)[idx] = o;
}

// P [2048][4096][2] f32  ->  PT [4096][4096] f16 where PT[m][n*2+p] = P[n][m][p]
__global__ __launch_bounds__(256) void transpose_p(const float* __restrict__ P,
                                                   unsigned short* __restrict__ PT) {
    __shared__ unsigned int lds[64][33];
    int bid = blockIdx.x;
    int m0 = (bid & 127) * 32;
    int n0 = (bid >> 7) * 64;
    int tid = threadIdx.x;
    const float2* P2 = (const float2*)P;
    #pragma unroll
    for (int it = 0; it < 8; ++it) {
        int idx = it * 256 + tid;
        int nl = idx >> 5, ml = idx & 31;
        float2 v = P2[(size_t)(n0 + nl) * 4096 + (m0 + ml)];
        unsigned int pk = (unsigned int)f16b(v.x) | ((unsigned int)f16b(v.y) << 16);
        lds[nl][ml] = pk;
    }
    __syncthreads();
    unsigned int* PTu = (unsigned int*)PT;
    #pragma unroll
    for (int it = 0; it < 8; ++it) {
        int idx = it * 256 + tid;
        int ml = idx >> 6, nl = idx & 63;
        PTu[(size_t)(m0 + ml) * 2048 + (n0 + nl)] = lds[nl][ml];
    }
}

// ---------------- per-layer B-matrix build, BN fused (fragment layout) ----------------
// Fragment layout: elem index ((t*2+h)*64+lane)*8+e holds B[k=t*32+(lane>>4)*8+e][g=h*16+(lane&15)]
__global__ __launch_bounds__(256) void build_b(
    const float* __restrict__ srcx, const float* __restrict__ srcy,
    int Fin, int Fout, int buildB2, int use_bn,
    const float* __restrict__ stats,
    const float* __restrict__ gx, const float* __restrict__ btx,
    const float* __restrict__ gy, const float* __restrict__ bty,
    const float* __restrict__ w1a, const float* __restrict__ w1b,
    const float* __restrict__ w2a, const float* __restrict__ w2b,
    unsigned short* __restrict__ B1f, unsigned short* __restrict__ B2f) {
    int tid0 = blockIdx.x * 256 + threadIdx.x;
    const int NB1 = 14336 * 32;
    int isB2 = 0, t2 = tid0;
    if (tid0 >= NB1) {
        if (!buildB2) return;
        isB2 = 1; t2 = tid0 - NB1;
        if (t2 >= 16384 * 32) return;
    }
    int e = t2 & 7, lane = (t2 >> 3) & 63, hh = (t2 >> 9) & 1, t = t2 >> 10;
    int k = (t << 5) | ((lane >> 4) << 3) | e;
    int g = (hh << 4) | (lane & 15);
    float v = 0.f;
    if (g < Fout) {
        const float* hr; const float* wc; int useY;
        if (!isB2) {
            if (k < 6144) { int m = k / 3, j = k - 3 * m; hr = srcx + m * Fin; wc = w1a + (j * Fin) * Fout + g; useY = 0; }
            else { int k2 = k - 6144; int m = k2 >> 1, p = k2 & 1; hr = srcy + m * Fin; wc = w1b + (p * Fin) * Fout + g; useY = 1; }
        } else {
            if (k < 12288) { int m = k / 3, j = k - 3 * m; hr = srcy + m * Fin; wc = w2a + (j * Fin) * Fout + g; useY = 1; }
            else { int k2 = k - 12288; int n = k2 >> 1, p = k2 & 1; hr = srcx + n * Fin; wc = w2b + (p * Fin) * Fout + g; useY = 0; }
        }
        float a = 0.f;
        if (use_bn) {
            const float* st = useY ? stats + 64 : stats;
            const float* gv = useY ? gy : gx;
            const float* bv = useY ? bty : btx;
            float invn = useY ? (1.f / 4096.f) : (1.f / 2048.f);
            #pragma unroll
            for (int f = 0; f < 32; ++f) {
                float mean = st[f] * invn;
                float var = st[32 + f] * invn - mean * mean;
                float sc = gv[f] * rsqrtf(var + 1e-5f);
                float h = sc * (hr[f] - mean) + bv[f];
                a += h * wc[f * Fout];
            }
        } else {
            for (int f = 0; f < Fin; ++f) a += hr[f] * wc[f * Fout];
        }
        v = a;
    }
    if (!isB2) B1f[t2] = f16b(v); else B2f[t2] = f16b(v);
}

// ---------------- split-K MFMA GEMM -> deterministic partials ----------------
// x-branch: 16 mwgs (128 rows) x 14 ksegs; y-branch: 32 mwgs x 16 ksegs
__global__ __launch_bounds__(256) void gemm_kernel(
    const unsigned short* __restrict__ Wb, const unsigned short* __restrict__ Pb,
    const unsigned short* __restrict__ WLb, const unsigned short* __restrict__ PTb,
    const unsigned short* __restrict__ B1f, const unsigned short* __restrict__ B2f,
    float* __restrict__ px, float* __restrict__ py, float* __restrict__ stats, int nwgx) {
    int bid = blockIdx.x;
    if (bid == 0 && threadIdx.x < 128) stats[threadIdx.x] = 0.f;  // pre-zero for next reduce
    const unsigned short *A1, *A2, *Bf;
    float* Z;
    int K1, K2len, split, seg, Mbase;
    if (bid < nwgx) {
        A1 = Wb; A2 = Pb; Bf = B1f;
        K1 = 6144; K2len = 8192; split = 6;
        int mwg = bid / 14; seg = bid % 14;
        Mbase = mwg * 128;
        Z = px + (size_t)seg * 65536;
    } else {
        int b2 = bid - nwgx;
        A1 = WLb; A2 = PTb; Bf = B2f;
        K1 = 12288; K2len = 4096; split = 12;
        int mwg = b2 / 16; seg = b2 % 16;
        Mbase = mwg * 128;
        Z = py + (size_t)seg * 131072;
    }
    int wid = threadIdx.x >> 6, lane = threadIdx.x & 63;
    int rowbase = Mbase + wid * 32;
    int kb = seg << 10;
    const unsigned short* Ab; int rowlen, kloc;
    if (seg < split) { Ab = A1; rowlen = K1; kloc = kb; }
    else             { Ab = A2; rowlen = K2len; kloc = kb - K1; }
    const unsigned short* ap0 = Ab + (size_t)(rowbase + (lane & 15)) * rowlen + kloc + ((lane >> 4) << 3);
    const unsigned short* ap1 = ap0 + (size_t)16 * rowlen;
    const unsigned short* bp = Bf + ((size_t)(kb >> 5)) * 1024 + lane * 8;
    f32x4 acc00 = {0.f,0.f,0.f,0.f}, acc01 = {0.f,0.f,0.f,0.f};
    f32x4 acc10 = {0.f,0.f,0.f,0.f}, acc11 = {0.f,0.f,0.f,0.f};
    #pragma unroll 4
    for (int ks = 0; ks < 32; ++ks) {
        f16x8 a0 = *(const f16x8*)ap0;
        f16x8 a1 = *(const f16x8*)ap1;
        f16x8 b0 = *(const f16x8*)bp;
        f16x8 b1 = *(const f16x8*)(bp + 512);
        acc00 = __builtin_amdgcn_mfma_f32_16x16x32_f16(a0, b0, acc00, 0, 0, 0);
        acc10 = __builtin_amdgcn_mfma_f32_16x16x32_f16(a1, b0, acc10, 0, 0, 0);
        acc01 = __builtin_amdgcn_mfma_f32_16x16x32_f16(a0, b1, acc01, 0, 0, 0);
        acc11 = __builtin_amdgcn_mfma_f32_16x16x32_f16(a1, b1, acc11, 0, 0, 0);
        ap0 += 32; ap1 += 32; bp += 1024;
    }
    int col = lane & 15, r0 = (lane >> 4) << 2;
    float* z0 = Z + (size_t)(rowbase + r0) * 32 + col;
    #pragma unroll
    for (int r = 0; r < 4; ++r) {
        z0[(size_t)r * 32]             = acc00[r];
        z0[(size_t)r * 32 + 16]        = acc01[r];
        z0[(size_t)(r + 16) * 32]      = acc10[r];
        z0[(size_t)(r + 16) * 32 + 16] = acc11[r];
    }
}

// ---------------- reduce partials + bias + relu-half + column stats ----------------
// blocks 0..63: x (65536 elems), 64..191: y (131072 elems); each thread one float4
__global__ __launch_bounds__(256) void reduce_stats(
    const float* __restrict__ px, const float* __restrict__ py,
    const float* __restrict__ bx, const float* __restrict__ by,
    float* __restrict__ zax, float* __restrict__ zay,
    float* __restrict__ stats) {
    __shared__ float lsum[4][8][8];
    int bid = blockIdx.x, tid = threadIdx.x;
    const float4* src; const float* bias; float4* dst; float* st; int nseg, i4, stride4;
    if (bid < 64) { src = (const float4*)px; bias = bx; dst = (float4*)zax; st = stats;      nseg = 14; i4 = bid * 256 + tid;        stride4 = 16384; }
    else          { src = (const float4*)py; bias = by; dst = (float4*)zay; st = stats + 64; nseg = 16; i4 = (bid - 64) * 256 + tid; stride4 = 32768; }
    float4 s = {0.f, 0.f, 0.f, 0.f};
    for (int g = 0; g < nseg; ++g) {
        float4 v = src[(size_t)g * stride4 + i4];
        s.x += v.x; s.y += v.y; s.z += v.z; s.w += v.w;
    }
    int c0 = (i4 & 7) * 4;
    float4 b4 = *(const float4*)(bias + c0);
    s.x += b4.x; s.y += b4.y; s.z += b4.z; s.w += b4.w;
    if (c0 < 16) {
        s.x = fmaxf(s.x, 0.f); s.y = fmaxf(s.y, 0.f);
        s.z = fmaxf(s.z, 0.f); s.w = fmaxf(s.w, 0.f);
    }
    dst[i4] = s;
    float4 s2 = {s.x * s.x, s.y * s.y, s.z * s.z, s.w * s.w};
    #pragma unroll
    for (int mask = 8; mask <= 32; mask <<= 1) {
        s.x += __shfl_xor(s.x, mask); s.y += __shfl_xor(s.y, mask);
        s.z += __shfl_xor(s.z, mask); s.w += __shfl_xor(s.w, mask);
        s2.x += __shfl_xor(s2.x, mask); s2.y += __shfl_xor(s2.y, mask);
        s2.z += __shfl_xor(s2.z, mask); s2.w += __shfl_xor(s2.w, mask);
    }
    int w = tid >> 6, ln = tid & 63;
    if (ln < 8) {
        lsum[w][ln][0] = s.x;  lsum[w][ln][1] = s.y;  lsum[w][ln][2] = s.z;  lsum[w][ln][3] = s.w;
        lsum[w][ln][4] = s2.x; lsum[w][ln][5] = s2.y; lsum[w][ln][6] = s2.z; lsum[w][ln][7] = s2.w;
    }
    __syncthreads();
    if (tid < 64) {
        int q = tid >> 3, e = tid & 7;
        float v = lsum[0][q][e] + lsum[1][q][e] + lsum[2][q][e] + lsum[3][q][e];
        int col = q * 4 + (e & 3);
        atomAddF((e < 4) ? &st[col] : &st[32 + col], v);
    }
}

// ---------------- final: sum x-partials + bl -> out ----------------
__global__ __launch_bounds__(256) void out_final(const float* __restrict__ px,
                                                 const float* __restrict__ bl,
                                                 float* __restrict__ out) {
    int tid = blockIdx.x * 256 + threadIdx.x;
    if (tid < 4096) {
        int n = tid >> 1, c = tid & 1;
        float a = bl[c];
        for (int s = 0; s < 14; ++s) a += px[(size_t)s * 65536 + n * 32 + c];
        out[tid] = a;
    }
}

extern "C" void kernel_launch(void* const* d_in, const int* in_sizes, int n_in,
                              void* d_out, int out_size, void* d_ws, size_t ws_size,
                              hipStream_t stream) {
    const float* W    = (const float*)d_in[0];
    const float* x    = (const float*)d_in[1];
    const float* WL   = (const float*)d_in[2];
    const float* y    = (const float*)d_in[3];
    const float* P    = (const float*)d_in[4];
    const float* wx2x0 = (const float*)d_in[5];
    const float* wy2x0 = (const float*)d_in[6];
    const float* bx0   = (const float*)d_in[7];
    const float* wy2y0 = (const float*)d_in[8];
    const float* wx2y0 = (const float*)d_in[9];
    const float* by0   = (const float*)d_in[10];
    const float* gx0   = (const float*)d_in[11];
    const float* btx0  = (const float*)d_in[12];
    const float* gy0   = (const float*)d_in[13];
    const float* bty0  = (const float*)d_in[14];
    const float* wx2x_m = (const float*)d_in[15];
    const float* wy2x_m = (const float*)d_in[16];
    const float* bx_m   = (const float*)d_in[17];
    const float* wy2y_m = (const float*)d_in[18];
    const float* wx2y_m = (const float*)d_in[19];
    const float* by_m   = (const float*)d_in[20];
    const float* gx_m   = (const float*)d_in[21];
    const float* btx_m  = (const float*)d_in[22];
    const float* gy_m   = (const float*)d_in[23];
    const float* bty_m  = (const float*)d_in[24];
    const float* wlx = (const float*)d_in[25];
    const float* wly = (const float*)d_in[26];
    const float* bl  = (const float*)d_in[27];

    char* base = (char*)d_ws;
    unsigned short* Wb  = (unsigned short*)(base + 0);          // 25,165,824 B
    unsigned short* Pb  = (unsigned short*)(base + 25165824);   // 33,554,432 B
    unsigned short* WLb = (unsigned short*)(base + 58720256);   // 100,663,296 B
    unsigned short* PTb = (unsigned short*)(base + 159383552);  // 33,554,432 B
    unsigned short* B1f = (unsigned short*)(base + 192937984);  // 917,504 B
    unsigned short* B2f = (unsigned short*)(base + 193855488);  // 1,048,576 B
    float* zax   = (float*)(base + 194904064);  // 262,144 B
    float* zay   = (float*)(base + 195166208);  // 524,288 B
    float* stats = (float*)(base + 195690496);  // 512 B
    float* px    = (float*)(base + 195691008);  // 14*65536*4  = 3,670,016 B
    float* py    = (float*)(base + 199361024);  // 16*131072*4 = 8,388,608 B

    // one-time conversions
    cvt_all<<<77824, 256, 0, stream>>>(W, P, WL, Wb, Pb, WLb);
    transpose_p<<<4096, 256, 0, stream>>>(P, PTb);

    // block 0 (Fin = 1, raw x/y, no bn)
    build_b<<<3840, 256, 0, stream>>>(x, y, 1, 32, 1, 0, nullptr, nullptr, nullptr, nullptr, nullptr,
                                      wx2x0, wy2x0, wy2y0, wx2y0, B1f, B2f);
    gemm_kernel<<<736, 256, 0, stream>>>(Wb, Pb, WLb, PTb, B1f, B2f, px, py, stats, 224);
    reduce_stats<<<192, 256, 0, stream>>>(px, py, bx0, by0, zax, zay, stats);

    // blocks 1..6 (middle weights i = 0..5); bn params of block i come from previous block
    for (int i = 0; i < 6; ++i) {
        const float* gv  = (i == 0) ? gx0  : gx_m  + (i - 1) * 32;
        const float* bv  = (i == 0) ? btx0 : btx_m + (i - 1) * 32;
        const float* gvy = (i == 0) ? gy0  : gy_m  + (i - 1) * 32;
        const float* bvy = (i == 0) ? bty0 : bty_m + (i - 1) * 32;
        build_b<<<3840, 256, 0, stream>>>(zax, zay, 32, 32, 1, 1, stats, gv, bv, gvy, bvy,
                                          wx2x_m + i * 3072, wy2x_m + i * 2048,
                                          wy2y_m + i * 3072, wx2y_m + i * 2048, B1f, B2f);
        gemm_kernel<<<736, 256, 0, stream>>>(Wb, Pb, WLb, PTb, B1f, B2f, px, py, stats, 224);
        reduce_stats<<<192, 256, 0, stream>>>(px, py, bx_m + i * 32, by_m + i * 32, zax, zay, stats);
    }

    // final layer: bn of block 6 (gx_m[5]...), linear weights, x-branch only
    build_b<<<1792, 256, 0, stream>>>(zax, zay, 32, 2, 0, 1, stats,
                                      gx_m + 5 * 32, btx_m + 5 * 32, gy_m + 5 * 32, bty_m + 5 * 32,
                                      wlx, wly, nullptr, nullptr, B1f, B2f);
    gemm_kernel<<<224, 256, 0, stream>>>(Wb, Pb, WLb, PTb, B1f, B2f, px, py, stats, 224);
    out_final<<<16, 256, 0, stream>>>(px, bl, (float*)d_out);
}